// Round 19
// baseline (1482.140 us; speedup 1.0000x reference)
//
#include <hip/hip_runtime.h>
#include <math.h>

// ---------------- constants ----------------
#define NTOK 4736
#define DM   768
#define NHEAD 12
#define KC   640          // conv K padded (588 -> 640)
#define LOG2E 1.44269504088896340736f

typedef __attribute__((ext_vector_type(8))) short bf16x8;
typedef __attribute__((ext_vector_type(4))) float f32x4;

__device__ inline short f2bf(float f) {
  union { float f; unsigned u; } v; v.f = f;
  unsigned r = v.u + 0x7FFF + ((v.u >> 16) & 1);   // RNE
  return (short)(r >> 16);
}
__device__ inline float bf2f(short s) {
  union { unsigned u; float f; } v; v.u = ((unsigned)(unsigned short)s) << 16;
  return v.f;
}

__device__ inline void gload16(const void* g, void* l) {
  __builtin_amdgcn_global_load_lds(
      (const __attribute__((address_space(1))) void*)g,
      (__attribute__((address_space(3))) void*)l, 16, 0, 0);
}

// ---------------- im2col ----------------
__global__ __launch_bounds__(256) void im2col_k(const float* __restrict__ x,
                                                short* __restrict__ col) {
  int i = blockIdx.x * 256 + threadIdx.x;
  int r = i / KC, k = i % KC;
  short v = 0;
  if (k < 588) {
    int bt = r / 36, p = r % 36;
    int gy = p / 6, gx = p % 6;
    int c = k / 196, rem = k % 196;
    int ky = rem / 14, kx = rem % 14;
    v = f2bf(x[(((size_t)bt * 3 + c) * 84 + gy * 14 + ky) * 84 + gx * 14 + kx]);
  }
  col[i] = v;
}

// ---------------- conv weight prep ----------------
__global__ __launch_bounds__(256) void convw_k(const float* __restrict__ w,
                                               short* __restrict__ out) {
  int i = blockIdx.x * 256 + threadIdx.x;
  int n = i / KC, k = i % KC;
  out[i] = (k < 588) ? f2bf(w[(size_t)n * 588 + k]) : (short)0;
}

// ---------------- weight transpose+convert ----------------
__global__ __launch_bounds__(256) void wt_k(const float* __restrict__ in,
                                            short* __restrict__ out,
                                            int K, int N) {
  __shared__ float tile[32][33];
  const int l = blockIdx.z;
  in  += (size_t)l * K * N;
  out += (size_t)l * N * K;
  const int n0 = blockIdx.x * 32, k0 = blockIdx.y * 32;
  const int tx = threadIdx.x & 31, ty = threadIdx.x >> 5;
#pragma unroll
  for (int r = 0; r < 4; r++)
    tile[ty + 8 * r][tx] = in[(size_t)(k0 + ty + 8 * r) * N + n0 + tx];
  __syncthreads();
#pragma unroll
  for (int r = 0; r < 4; r++)
    out[(size_t)(n0 + ty + 8 * r) * K + k0 + tx] = f2bf(tile[tx][ty + 8 * r]);
}

// ---------------- token assembly ----------------
__global__ __launch_bounds__(256) void assemble_k(const float* __restrict__ conv_out,
                                                  const float* __restrict__ cls,
                                                  const float* __restrict__ pos,
                                                  float* __restrict__ X) {
  int i = blockIdx.x * 256 + threadIdx.x;
  int t = i / DM, d = i % DM;
  int bt = t / 37, n = t % 37;
  float v = (n == 0) ? cls[d] : conv_out[((size_t)bt * 36 + (n - 1)) * DM + d];
  X[i] = v + pos[n * DM + d];
}

// ---------------- temporal pos add ----------------
__global__ __launch_bounds__(256) void tpos_k(float* __restrict__ X,
                                              const float* __restrict__ tpos) {
  int i = blockIdx.x * 256 + threadIdx.x;
  int row = i / DM, d = i % DM;
  int tt = (row % 1184) / 37;
  X[i] += tpos[tt * DM + d];
}

// ---------------- LayerNorm ----------------
template <bool OBF>
__global__ __launch_bounds__(256) void ln_k(const float* __restrict__ in,
                                            const float* __restrict__ g,
                                            const float* __restrict__ b,
                                            void* __restrict__ outp) {
  int r = blockIdx.x;
  int tid = threadIdx.x;
  const float* xr = in + (size_t)r * DM;
  float v0 = xr[tid], v1 = xr[tid + 256], v2 = xr[tid + 512];
  float s  = v0 + v1 + v2;
  float sq = v0 * v0 + v1 * v1 + v2 * v2;
#pragma unroll
  for (int off = 32; off; off >>= 1) {
    s  += __shfl_down(s, off);
    sq += __shfl_down(sq, off);
  }
  __shared__ float ss[4], sg[4];
  if ((tid & 63) == 0) { ss[tid >> 6] = s; sg[tid >> 6] = sq; }
  __syncthreads();
  float S = ss[0] + ss[1] + ss[2] + ss[3];
  float Q = sg[0] + sg[1] + sg[2] + sg[3];
  float mean = S * (1.f / 768.f);
  float var  = Q * (1.f / 768.f) - mean * mean;
  float rs = rsqrtf(var + 1e-5f);
  float o0 = (v0 - mean) * rs * g[tid]       + b[tid];
  float o1 = (v1 - mean) * rs * g[tid + 256] + b[tid + 256];
  float o2 = (v2 - mean) * rs * g[tid + 512] + b[tid + 512];
  if (OBF) {
    short* o = (short*)outp + (size_t)r * DM;
    o[tid] = f2bf(o0); o[tid + 256] = f2bf(o1); o[tid + 512] = f2bf(o2);
  } else {
    float* o = (float*)outp + (size_t)r * DM;
    o[tid] = o0; o[tid + 256] = o1; o[tid + 512] = o2;
  }
}

// ---------------- fused double LayerNorm ----------------
__global__ __launch_bounds__(256) void ln2_k(const float* __restrict__ in,
                                             const float* __restrict__ g1,
                                             const float* __restrict__ b1,
                                             const float* __restrict__ g2,
                                             const float* __restrict__ b2,
                                             float* __restrict__ xn,
                                             short* __restrict__ w) {
  int r = blockIdx.x;
  int tid = threadIdx.x;
  const float* xr = in + (size_t)r * DM;
  float v0 = xr[tid], v1 = xr[tid + 256], v2 = xr[tid + 512];
  float s  = v0 + v1 + v2;
  float sq = v0 * v0 + v1 * v1 + v2 * v2;
#pragma unroll
  for (int off = 32; off; off >>= 1) {
    s  += __shfl_down(s, off);
    sq += __shfl_down(sq, off);
  }
  __shared__ float ss[4], sg[4], ss2[4], sg2[4];
  if ((tid & 63) == 0) { ss[tid >> 6] = s; sg[tid >> 6] = sq; }
  __syncthreads();
  float S = ss[0] + ss[1] + ss[2] + ss[3];
  float Q = sg[0] + sg[1] + sg[2] + sg[3];
  float mean = S * (1.f / 768.f);
  float var  = Q * (1.f / 768.f) - mean * mean;
  float rs = rsqrtf(var + 1e-5f);
  float x0 = (v0 - mean) * rs * g1[tid]       + b1[tid];
  float x1 = (v1 - mean) * rs * g1[tid + 256] + b1[tid + 256];
  float x2 = (v2 - mean) * rs * g1[tid + 512] + b1[tid + 512];
  float* xo = xn + (size_t)r * DM;
  xo[tid] = x0; xo[tid + 256] = x1; xo[tid + 512] = x2;
  float s2  = x0 + x1 + x2;
  float sq2 = x0 * x0 + x1 * x1 + x2 * x2;
#pragma unroll
  for (int off = 32; off; off >>= 1) {
    s2  += __shfl_down(s2, off);
    sq2 += __shfl_down(sq2, off);
  }
  if ((tid & 63) == 0) { ss2[tid >> 6] = s2; sg2[tid >> 6] = sq2; }
  __syncthreads();
  float S2 = ss2[0] + ss2[1] + ss2[2] + ss2[3];
  float Q2 = sg2[0] + sg2[1] + sg2[2] + sg2[3];
  float mean2 = S2 * (1.f / 768.f);
  float var2  = Q2 * (1.f / 768.f) - mean2 * mean2;
  float rs2 = rsqrtf(var2 + 1e-5f);
  short* wo = w + (size_t)r * DM;
  wo[tid]       = f2bf((x0 - mean2) * rs2 * g2[tid]       + b2[tid]);
  wo[tid + 256] = f2bf((x1 - mean2) * rs2 * g2[tid + 256] + b2[tid + 256]);
  wo[tid + 512] = f2bf((x2 - mean2) * rs2 * g2[tid + 512] + b2[tid + 512]);
}

// ---------------- MFMA bf16 GEMM: BK=32, 2-slot counted vmcnt (r16 best) ----
template <int BM, int BN, bool GELU, bool OBF, bool HASR1, bool HASR2>
__global__ __launch_bounds__(256, 4) void tgemm_k(const short* __restrict__ A,
                                                  const short* __restrict__ Bw,
                                                  const float* __restrict__ bias,
                                                  const float* __restrict__ r1,
                                                  const float* __restrict__ r2,
                                                  void* __restrict__ Cout,
                                                  int M, int N, int K) {
  constexpr int TM = BM / 2, TN = BN / 2;      // 2x2 waves
  constexpr int MF = TM / 16, NF = TN / 16;
  constexpr int ACH = BM / 64, BCH = BN / 64;
  constexpr int LOADS = ACH + BCH;

  __shared__ short As[2][BM][32];
  __shared__ short Bs[2][BN][32];

  const int nwg  = gridDim.x * gridDim.y;
  const int orig = blockIdx.x + gridDim.x * blockIdx.y;
  const int qq = nwg >> 3, rrm = nwg & 7;
  const int xcd = orig & 7, sub = orig >> 3;
  const int wgid = ((xcd < rrm) ? xcd * (qq + 1) : rrm * (qq + 1) + (xcd - rrm) * qq) + sub;
  const int bm = (wgid / gridDim.y) * BM, bn = (wgid % gridDim.y) * BN;

  const int tid = threadIdx.x, wid = tid >> 6, lane = tid & 63;
  const int lr = lane & 15, lg = lane >> 4;
  const int wm = wid >> 1, wn = wid & 1;

  const int srow = tid >> 2;
  const int sslot = (tid & 3) ^ ((srow >> 1) & 3);
  const short* Asrc = A  + (size_t)(bm + srow) * K + sslot * 8;
  const short* Bsrc = Bw + (size_t)(bn + srow) * K + sslot * 8;

  f32x4 acc[MF][NF];
#pragma unroll
  for (int m = 0; m < MF; m++)
#pragma unroll
    for (int n = 0; n < NF; n++) acc[m][n] = (f32x4){0.f, 0.f, 0.f, 0.f};

#define STAGE(slot, kk)                                                        \
  do {                                                                         \
    _Pragma("unroll")                                                          \
    for (int j = 0; j < ACH; j++)                                              \
      gload16(Asrc + (size_t)(j * 64) * K + (kk),                              \
              (char*)&As[slot][0][0] + j * 4096 + wid * 1024);                 \
    _Pragma("unroll")                                                          \
    for (int j = 0; j < BCH; j++)                                              \
      gload16(Bsrc + (size_t)(j * 64) * K + (kk),                              \
              (char*)&Bs[slot][0][0] + j * 4096 + wid * 1024);                 \
  } while (0)

  const int NT = K >> 5;
  const int rkey = (lr >> 1) & 3;

  STAGE(0, 0);
  for (int t = 0; t < NT; t++) {
    const int c = t & 1;
    if (t + 1 < NT) {
      STAGE(c ^ 1, (t + 1) << 5);
      if constexpr (LOADS == 4) asm volatile("s_waitcnt vmcnt(4)" ::: "memory");
      else                      asm volatile("s_waitcnt vmcnt(2)" ::: "memory");
    } else {
      asm volatile("s_waitcnt vmcnt(0)" ::: "memory");
    }
    __builtin_amdgcn_s_barrier();               // slot-c data visible to all

    bf16x8 aq[MF], bq[NF];
#pragma unroll
    for (int nf = 0; nf < NF; nf++) {
      const int row = wn * TN + nf * 16 + lr;
      bq[nf] = *reinterpret_cast<const bf16x8*>(
          (const char*)&Bs[c][0][0] + row * 64 + ((lg ^ rkey) << 4));
    }
#pragma unroll
    for (int mf = 0; mf < MF; mf++) {
      const int row = wm * TM + mf * 16 + lr;
      aq[mf] = *reinterpret_cast<const bf16x8*>(
          (const char*)&As[c][0][0] + row * 64 + ((lg ^ rkey) << 4));
    }
    __builtin_amdgcn_s_setprio(1);
#pragma unroll
    for (int mf = 0; mf < MF; mf++)
#pragma unroll
      for (int nf = 0; nf < NF; nf++)
        acc[mf][nf] = __builtin_amdgcn_mfma_f32_16x16x32_bf16(
            aq[mf], bq[nf], acc[mf][nf], 0, 0, 0);
    __builtin_amdgcn_s_setprio(0);
    __builtin_amdgcn_s_barrier();               // reads done before overwrite
  }
#undef STAGE

#pragma unroll
  for (int m = 0; m < MF; m++) {
#pragma unroll
    for (int r = 0; r < 4; r++) {
      int row = bm + wm * TM + m * 16 + lg * 4 + r;
      if (row < M) {
#pragma unroll
        for (int n = 0; n < NF; n++) {
          int col = bn + wn * TN + n * 16 + lr;
          size_t idx = (size_t)row * N + col;
          float v = acc[m][n][r];
          if (bias) v += bias[col];
          if (GELU) v = 0.5f * v * (1.f + erff(v * 0.70710678118654752f));
          if (HASR1) v += r1[idx];
          if (HASR2) v += r2[idx];
          if (OBF) ((short*)Cout)[idx] = f2bf(v);
          else     ((float*)Cout)[idx] = v;
        }
      }
    }
  }
}

// ---------------- attn v2-KV64 (spatial): exp2-domain softmax ----------------
__global__ __launch_bounds__(256) void attn64_k(const short* __restrict__ qkv,
                                                short* __restrict__ out,
                                                int Bn, int Nn) {
  const int gx = gridDim.x, gy = gridDim.y;
  const int nwg = gx * gy;
  const int orig = blockIdx.x + gx * blockIdx.y;
  const int qq = nwg >> 3, rrm = nwg & 7;
  const int xcd = orig & 7, sub = orig >> 3;
  const int wgid = ((xcd < rrm) ? xcd * (qq + 1) : rrm * (qq + 1) + (xcd - rrm) * qq) + sub;
  const int bh = wgid / gy;
  const int qb = wgid % gy;
  const int b = bh / NHEAD, h = bh % NHEAD;
  const int q0 = qb * 64;

  const int tid = threadIdx.x;
  const int wid = tid >> 6, lane = tid & 63;
  const int lr = lane & 15, lg = lane >> 4;

  __shared__ short Ks[64][64];
  __shared__ short Vt[64][64];
  __shared__ short Ps[4][16][64];

  const int qrow_in = q0 + wid * 16 + lr;
  const int qcl = (qrow_in < Nn) ? qrow_in : (Nn - 1);
  const short* qp = qkv + ((size_t)(b * Nn + qcl)) * 2304 + h * 64 + lg * 8;
  bf16x8 qa0 = *reinterpret_cast<const bf16x8*>(qp);
  bf16x8 qa1 = *reinterpret_cast<const bf16x8*>(qp + 32);

  f32x4 oo[4];
#pragma unroll
  for (int dg = 0; dg < 4; dg++) oo[dg] = (f32x4){0.f, 0.f, 0.f, 0.f};
  float mm[4] = {-1e30f, -1e30f, -1e30f, -1e30f};
  float ll[4] = {0.f, 0.f, 0.f, 0.f};

  const int skey = tid >> 2;
  const int sdq  = (tid & 3) * 16;
  const int vkey = tid & 63;
  const int vd0  = wid * 16;

  const int swr = (lr & 7) << 3;

  for (int k0 = 0; k0 < Nn; k0 += 64) {
    {
      int kg = k0 + skey; if (kg >= Nn) kg = Nn - 1;
      const short* kp = qkv + ((size_t)(b * Nn + kg)) * 2304 + 768 + h * 64 + sdq;
      bf16x8 ka = *reinterpret_cast<const bf16x8*>(kp);
      bf16x8 kb = *reinterpret_cast<const bf16x8*>(kp + 8);
      const int ksw = (skey & 7) << 3;
      *reinterpret_cast<bf16x8*>(&Ks[skey][sdq ^ ksw])       = ka;
      *reinterpret_cast<bf16x8*>(&Ks[skey][(sdq + 8) ^ ksw]) = kb;
      int vg = k0 + vkey; if (vg >= Nn) vg = Nn - 1;
      const short* vp = qkv + ((size_t)(b * Nn + vg)) * 2304 + 1536 + h * 64 + vd0;
      bf16x8 va = *reinterpret_cast<const bf16x8*>(vp);
      bf16x8 vb = *reinterpret_cast<const bf16x8*>(vp + 8);
#pragma unroll
      for (int i = 0; i < 8; i++) {
        Vt[vd0 + i][vkey ^ (i << 3)]     = va[i];
        Vt[vd0 + 8 + i][vkey ^ (i << 3)] = vb[i];
      }
    }
    __syncthreads();

    f32x4 c[4];
#pragma unroll
    for (int kf = 0; kf < 4; kf++) {
      c[kf] = (f32x4){0.f, 0.f, 0.f, 0.f};
      const short* krow = &Ks[kf * 16 + lr][0];
      bf16x8 kb0 = *reinterpret_cast<const bf16x8*>(krow + ((lg * 8) ^ swr));
      c[kf] = __builtin_amdgcn_mfma_f32_16x16x32_bf16(qa0, kb0, c[kf], 0, 0, 0);
      bf16x8 kb1 = *reinterpret_cast<const bf16x8*>(krow + ((32 + lg * 8) ^ swr));
      c[kf] = __builtin_amdgcn_mfma_f32_16x16x32_bf16(qa1, kb1, c[kf], 0, 0, 0);
    }
#pragma unroll
    for (int kf = 0; kf < 4; kf++) {
#pragma unroll
      for (int r = 0; r < 4; r++) c[kf][r] *= (0.125f * LOG2E);  // log2 domain
      if (k0 + kf * 16 + lr >= Nn)
        c[kf][0] = c[kf][1] = c[kf][2] = c[kf][3] = -1e30f;
    }

    float tr[4];
#pragma unroll
    for (int r = 0; r < 4; r++) {
      float tv = fmaxf(fmaxf(c[0][r], c[1][r]), fmaxf(c[2][r], c[3][r]));
      tv = fmaxf(tv, __shfl_xor(tv, 1, 16));
      tv = fmaxf(tv, __shfl_xor(tv, 2, 16));
      tv = fmaxf(tv, __shfl_xor(tv, 4, 16));
      tv = fmaxf(tv, __shfl_xor(tv, 8, 16));
      tr[r] = tv;
    }
    const bool skipall = __all((tr[0] - mm[0] <= 8.f) & (tr[1] - mm[1] <= 8.f) &
                               (tr[2] - mm[2] <= 8.f) & (tr[3] - mm[3] <= 8.f));
#pragma unroll
    for (int r = 0; r < 4; r++) {
      if (!skipall) {
        float mn = fmaxf(mm[r], tr[r]);
        float sc = exp2f(mm[r] - mn);
        ll[r] *= sc;
        oo[0][r] *= sc; oo[1][r] *= sc; oo[2][r] *= sc; oo[3][r] *= sc;
        mm[r] = mn;
      }
      float p0 = exp2f(c[0][r] - mm[r]);
      float p1 = exp2f(c[1][r] - mm[r]);
      float p2 = exp2f(c[2][r] - mm[r]);
      float p3 = exp2f(c[3][r] - mm[r]);
      float ps = (p0 + p1) + (p2 + p3);
      ps += __shfl_xor(ps, 1, 16);
      ps += __shfl_xor(ps, 2, 16);
      ps += __shfl_xor(ps, 4, 16);
      ps += __shfl_xor(ps, 8, 16);
      ll[r] += ps;
      const int prow = lg * 4 + r;
      const int psw  = (prow & 7) << 3;
      short* pr = &Ps[wid][prow][0];
      pr[lr ^ psw]        = f2bf(p0);
      pr[(16 + lr) ^ psw] = f2bf(p1);
      pr[(32 + lr) ^ psw] = f2bf(p2);
      pr[(48 + lr) ^ psw] = f2bf(p3);
    }

#pragma unroll
    for (int ks = 0; ks < 2; ks++) {
      bf16x8 pa = *reinterpret_cast<const bf16x8*>(&Ps[wid][lr][(ks * 32 + lg * 8) ^ swr]);
#pragma unroll
      for (int dg = 0; dg < 4; dg++) {
        bf16x8 vb = *reinterpret_cast<const bf16x8*>(
            &Vt[dg * 16 + lr][(ks * 32 + lg * 8) ^ swr]);
        oo[dg] = __builtin_amdgcn_mfma_f32_16x16x32_bf16(pa, vb, oo[dg], 0, 0, 0);
      }
    }
    __syncthreads();
  }

#pragma unroll
  for (int r = 0; r < 4; r++) {
    int qr = q0 + wid * 16 + lg * 4 + r;
    if (qr < Nn) {
      float inv = 1.f / ll[r];
      short* op = out + ((size_t)(b * Nn + qr)) * DM + h * 64 + lr;
      op[0]  = f2bf(oo[0][r] * inv);
      op[16] = f2bf(oo[1][r] * inv);
      op[32] = f2bf(oo[2][r] * inv);
      op[48] = f2bf(oo[3][r] * inv);
    }
  }
}

// ---------------- attn v3-Q128-KV128 (temporal): exp2-domain softmax ---------
__global__ __launch_bounds__(512) void attnT_k(const short* __restrict__ qkv,
                                               short* __restrict__ out,
                                               int Bn, int Nn) {
  const int gx = gridDim.x, gy = gridDim.y;
  const int nwg = gx * gy;
  const int orig = blockIdx.x + gx * blockIdx.y;
  const int qq = nwg >> 3, rrm = nwg & 7;
  const int xcd = orig & 7, sub = orig >> 3;
  const int wgid = ((xcd < rrm) ? xcd * (qq + 1) : rrm * (qq + 1) + (xcd - rrm) * qq) + sub;
  const int bh = wgid / gy;
  const int qb = wgid % gy;
  const int b = bh / NHEAD, h = bh % NHEAD;
  const int q0 = qb * 128;

  const int tid = threadIdx.x;
  const int wid = tid >> 6, lane = tid & 63;     // wid 0..7
  const int lr = lane & 15, lg = lane >> 4;

  __shared__ short Ks[128][64];     // 16KB
  __shared__ short Vt[64][128];     // 16KB
  __shared__ short Ps[8][16][128];  // 32KB

  const int qrow_in = q0 + wid * 16 + lr;
  const int qcl = (qrow_in < Nn) ? qrow_in : (Nn - 1);
  const short* qp = qkv + ((size_t)(b * Nn + qcl)) * 2304 + h * 64 + lg * 8;
  bf16x8 qa0 = *reinterpret_cast<const bf16x8*>(qp);
  bf16x8 qa1 = *reinterpret_cast<const bf16x8*>(qp + 32);
#pragma unroll
  for (int j = 0; j < 8; j++) {      // fold 1/8 * log2e into Q: scores in log2
    qa0[j] = f2bf(bf2f(qa0[j]) * (0.125f * LOG2E));
    qa1[j] = f2bf(bf2f(qa1[j]) * (0.125f * LOG2E));
  }

  f32x4 oo[4];
#pragma unroll
  for (int dg = 0; dg < 4; dg++) oo[dg] = (f32x4){0.f, 0.f, 0.f, 0.f};
  float mm[4] = {-1e30f, -1e30f, -1e30f, -1e30f};
  float ll[4] = {0.f, 0.f, 0.f, 0.f};

  const int skey = tid >> 2;            // K: key row 0..127
  const int sdq  = (tid & 3) * 16;      // K: d offset 0/16/32/48
  const int vkeyc = tid & 127;          // V: key 0..127
  const int vd0   = (tid >> 7) * 16;    // V: d range via tid bits 7-8
  const int swr = (lr & 7) << 3;
  const int ksw = (skey & 7) << 3;

  for (int k0 = 0; k0 < Nn; k0 += 128) {
    {
      int kg = k0 + skey; if (kg >= Nn) kg = Nn - 1;
      const short* kp = qkv + ((size_t)(b * Nn + kg)) * 2304 + 768 + h * 64 + sdq;
      bf16x8 k0v = *reinterpret_cast<const bf16x8*>(kp);
      bf16x8 k1v = *reinterpret_cast<const bf16x8*>(kp + 8);
      *reinterpret_cast<bf16x8*>(&Ks[skey][(sdq +  0) ^ ksw]) = k0v;
      *reinterpret_cast<bf16x8*>(&Ks[skey][(sdq +  8) ^ ksw]) = k1v;
      int vg = k0 + vkeyc; if (vg >= Nn) vg = Nn - 1;
      const short* vp = qkv + ((size_t)(b * Nn + vg)) * 2304 + 1536 + h * 64 + vd0;
      bf16x8 v0 = *reinterpret_cast<const bf16x8*>(vp);
      bf16x8 v1 = *reinterpret_cast<const bf16x8*>(vp + 8);
#pragma unroll
      for (int i = 0; i < 8; i++) {
        Vt[vd0 + i]    [vkeyc ^ (i << 3)] = v0[i];
        Vt[vd0 + 8 + i][vkeyc ^ (i << 3)] = v1[i];
      }
    }
    __syncthreads();

    f32x4 c[8];
#pragma unroll
    for (int kf = 0; kf < 8; kf++) {
      c[kf] = (f32x4){0.f, 0.f, 0.f, 0.f};
      const short* krow = &Ks[kf * 16 + lr][0];
      bf16x8 kq0 = *reinterpret_cast<const bf16x8*>(krow + ((lg * 8) ^ swr));
      c[kf] = __builtin_amdgcn_mfma_f32_16x16x32_bf16(qa0, kq0, c[kf], 0, 0, 0);
      bf16x8 kq1 = *reinterpret_cast<const bf16x8*>(krow + ((32 + lg * 8) ^ swr));
      c[kf] = __builtin_amdgcn_mfma_f32_16x16x32_bf16(qa1, kq1, c[kf], 0, 0, 0);
    }
#pragma unroll
    for (int kf = 0; kf < 8; kf++) {
      if (k0 + kf * 16 + lr >= Nn)
        c[kf][0] = c[kf][1] = c[kf][2] = c[kf][3] = -1e30f;
    }

    float tr[4];
#pragma unroll
    for (int r = 0; r < 4; r++) {
      float tv = fmaxf(fmaxf(fmaxf(c[0][r], c[1][r]), fmaxf(c[2][r], c[3][r])),
                       fmaxf(fmaxf(c[4][r], c[5][r]), fmaxf(c[6][r], c[7][r])));
      tv = fmaxf(tv, __shfl_xor(tv, 1, 16));
      tv = fmaxf(tv, __shfl_xor(tv, 2, 16));
      tv = fmaxf(tv, __shfl_xor(tv, 4, 16));
      tv = fmaxf(tv, __shfl_xor(tv, 8, 16));
      tr[r] = tv;
    }
    const bool skipall = __all((tr[0] - mm[0] <= 8.f) & (tr[1] - mm[1] <= 8.f) &
                               (tr[2] - mm[2] <= 8.f) & (tr[3] - mm[3] <= 8.f));
#pragma unroll
    for (int r = 0; r < 4; r++) {
      if (!skipall) {
        float mn = fmaxf(mm[r], tr[r]);
        float sc = exp2f(mm[r] - mn);
        ll[r] *= sc;
        oo[0][r] *= sc; oo[1][r] *= sc; oo[2][r] *= sc; oo[3][r] *= sc;
        mm[r] = mn;
      }
      float p[8], ps = 0.f;
#pragma unroll
      for (int kf = 0; kf < 8; kf++) {
        p[kf] = exp2f(c[kf][r] - mm[r]);
        ps += p[kf];
      }
      ps += __shfl_xor(ps, 1, 16);
      ps += __shfl_xor(ps, 2, 16);
      ps += __shfl_xor(ps, 4, 16);
      ps += __shfl_xor(ps, 8, 16);
      ll[r] += ps;
      const int prow = lg * 4 + r;
      const int psw  = (prow & 7) << 3;
      short* pr = &Ps[wid][prow][0];
#pragma unroll
      for (int kf = 0; kf < 8; kf++)
        pr[(kf * 16 + lr) ^ psw] = f2bf(p[kf]);
    }

#pragma unroll
    for (int ks = 0; ks < 4; ks++) {
      bf16x8 pa = *reinterpret_cast<const bf16x8*>(
          &Ps[wid][lr][(ks * 32 + lg * 8) ^ swr]);
#pragma unroll
      for (int dg = 0; dg < 4; dg++) {
        bf16x8 vq = *reinterpret_cast<const bf16x8*>(
            &Vt[dg * 16 + lr][(ks * 32 + lg * 8) ^ swr]);
        oo[dg] = __builtin_amdgcn_mfma_f32_16x16x32_bf16(pa, vq, oo[dg], 0, 0, 0);
      }
    }
    __syncthreads();
  }

#pragma unroll
  for (int r = 0; r < 4; r++) {
    int qr = q0 + wid * 16 + lg * 4 + r;
    if (qr < Nn) {
      float inv = 1.f / ll[r];
      short* op = out + ((size_t)(b * Nn + qr)) * DM + h * 64 + lr;
      op[0]  = f2bf(oo[0][r] * inv);
      op[16] = f2bf(oo[1][r] * inv);
      op[32] = f2bf(oo[2][r] * inv);
      op[48] = f2bf(oo[3][r] * inv);
    }
  }
}

// ---------------- mean over sequence, two-pass ----------------
__global__ __launch_bounds__(256) void mean1_k(const float* __restrict__ X,
                                               float* __restrict__ P) {
  int b = blockIdx.x, seg = blockIdx.z;
  int d = blockIdx.y * 256 + threadIdx.x;
  int r0 = seg * 148;
  float s = 0.f;
  for (int r = r0; r < r0 + 148; r++) s += X[((size_t)b * 1184 + r) * DM + d];
  P[((size_t)(b * 8 + seg)) * DM + d] = s;
}
__global__ __launch_bounds__(256) void mean2_k(const float* __restrict__ P,
                                               float* __restrict__ out) {
  int b = blockIdx.x;
  int d = blockIdx.y * 256 + threadIdx.x;
  float s = 0.f;
#pragma unroll
  for (int seg = 0; seg < 8; seg++) s += P[((size_t)(b * 8 + seg)) * DM + d];
  out[b * DM + d] = s * (1.f / 1184.f);
}

// ---------------- orchestration ----------------
extern "C" void kernel_launch(void* const* d_in, const int* in_sizes, int n_in,
                              void* d_out, int out_size, void* d_ws, size_t ws_size,
                              hipStream_t stream) {
  (void)in_sizes; (void)n_in; (void)out_size; (void)ws_size;
  const float* x      = (const float*)d_in[0];
  const float* conv_w = (const float*)d_in[1];
  const float* conv_b = (const float*)d_in[2];
  const float* cls    = (const float*)d_in[3];
  const float* pos    = (const float*)d_in[4];
  const float* tpos   = (const float*)d_in[5];
  const float* W[2][14];
  for (int p = 0; p < 2; p++)
    for (int i = 0; i < 14; i++)
      W[p][i] = (const float*)d_in[6 + p * 14 + i];

  char* ws = (char*)d_ws;
  const size_t TOKF = (size_t)NTOK * DM * 4;
  float* X    = (float*)(ws);
  float* XN   = (float*)(ws + TOKF);
  float* Y    = (float*)(ws + 2 * TOKF);
  short* TA2  = (short*)(ws + 3 * TOKF);
  short* BIG  = (short*)(ws + 3 * TOKF + (size_t)NTOK * DM * 2);
  short* WB   = (short*)(ws + 3 * TOKF + (size_t)NTOK * DM * 2
                            + (size_t)NTOK * 3072 * 2);
  const size_t QE = (size_t)3 * 2304 * 768;
  const size_t PE = (size_t)3 * 768 * 768;
  const size_t F1E = (size_t)3 * 3072 * 768;
  const size_t F2E = (size_t)3 * 768 * 3072;
  const size_t PFX = QE + PE + F1E + F2E;
  short* WQ[2], *WP[2], *WF1[2], *WF2[2];
  for (int p = 0; p < 2; p++) {
    WQ[p]  = WB + p * PFX;
    WP[p]  = WQ[p] + QE;
    WF1[p] = WP[p] + PE;
    WF2[p] = WF1[p] + F1E;
  }
  short* CW = WB + 2 * PFX;
  float* PB = (float*)(CW + (size_t)768 * KC);

  for (int p = 0; p < 2; p++) {
    wt_k<<<dim3(72, 24, 3), 256, 0, stream>>>(W[p][4],  WQ[p],  768, 2304);
    wt_k<<<dim3(24, 24, 3), 256, 0, stream>>>(W[p][6],  WP[p],  768, 768);
    wt_k<<<dim3(96, 24, 3), 256, 0, stream>>>(W[p][10], WF1[p], 768, 3072);
    wt_k<<<dim3(24, 96, 3), 256, 0, stream>>>(W[p][12], WF2[p], 3072, 768);
  }
  convw_k<<<1920, 256, 0, stream>>>(conv_w, CW);

  im2col_k<<<11520, 256, 0, stream>>>(x, BIG);
  tgemm_k<64, 64, false, false, false, false><<<dim3(72, 12), 256, 0, stream>>>(
      BIG, CW, conv_b, nullptr, nullptr, Y, 4608, 768, KC);
  assemble_k<<<14208, 256, 0, stream>>>(Y, cls, pos, X);

  for (int phase = 0; phase < 2; phase++) {
    const int Bn = (phase == 0) ? 128 : 4;
    const int Nn = (phase == 0) ? 37 : 1184;
    if (phase == 1) tpos_k<<<14208, 256, 0, stream>>>(X, tpos);
    for (int i = 0; i < 3; i++) {
      const float* pre_g = W[phase][0] + i * DM;
      const float* pre_b = W[phase][1] + i * DM;
      const float* n1_g  = W[phase][2] + i * DM;
      const float* n1_b  = W[phase][3] + i * DM;
      const float* qkv_b = W[phase][5] + i * 2304;
      const float* prj_b = W[phase][7] + i * DM;
      const float* n2_g  = W[phase][8] + i * DM;
      const float* n2_b  = W[phase][9] + i * DM;
      const float* fc1_b = W[phase][11] + i * 3072;
      const float* fc2_b = W[phase][13] + i * DM;
      const short* qkv_w = WQ[phase]  + (size_t)i * 2304 * 768;
      const short* prj_w = WP[phase]  + (size_t)i * 768 * 768;
      const short* fc1_w = WF1[phase] + (size_t)i * 3072 * 768;
      const short* fc2_w = WF2[phase] + (size_t)i * 768 * 3072;

      ln2_k<<<NTOK, 256, 0, stream>>>(X, pre_g, pre_b, n1_g, n1_b, XN, TA2);
      tgemm_k<128, 128, false, true, false, false><<<dim3(37, 18), 256, 0, stream>>>(
          TA2, qkv_w, qkv_b, nullptr, nullptr, BIG, NTOK, 2304, DM);
      if (phase == 0)
        attn64_k<<<dim3(Bn * NHEAD, (Nn + 63) / 64), 256, 0, stream>>>(BIG, TA2, Bn, Nn);
      else
        attnT_k<<<dim3(Bn * NHEAD, (Nn + 127) / 128), 512, 0, stream>>>(BIG, TA2, Bn, Nn);
      tgemm_k<64, 64, false, false, true, false><<<dim3(74, 12), 256, 0, stream>>>(
          TA2, prj_w, prj_b, XN, nullptr, Y, NTOK, DM, DM);
      ln_k<true><<<NTOK, 256, 0, stream>>>(Y, n2_g, n2_b, TA2);
      tgemm_k<128, 128, true, true, false, false><<<dim3(37, 24), 256, 0, stream>>>(
          TA2, fc1_w, fc1_b, nullptr, nullptr, BIG, NTOK, 3072, DM);
      tgemm_k<64, 64, false, false, true, true><<<dim3(74, 12), 256, 0, stream>>>(
          BIG, fc2_w, fc2_b, Y, X, X, NTOK, DM, 3072);
    }
  }
  mean1_k<<<dim3(4, 3, 8), 256, 0, stream>>>(X, PB);
  mean2_k<<<dim3(4, 3), 256, 0, stream>>>(PB, (float*)d_out);
}

// Round 20
// 1455.271 us; speedup vs baseline: 1.0185x; 1.0185x over previous
//
#include <hip/hip_runtime.h>
#include <math.h>

// ---------------- constants ----------------
#define NTOK 4736
#define DM   768
#define NHEAD 12
#define KC   640          // conv K padded (588 -> 640)
#define LOG2E 1.44269504088896340736f

typedef __attribute__((ext_vector_type(8))) short bf16x8;
typedef __attribute__((ext_vector_type(4))) float f32x4;

__device__ inline short f2bf(float f) {
  union { float f; unsigned u; } v; v.f = f;
  unsigned r = v.u + 0x7FFF + ((v.u >> 16) & 1);   // RNE
  return (short)(r >> 16);
}
__device__ inline float bf2f(short s) {
  union { unsigned u; float f; } v; v.u = ((unsigned)(unsigned short)s) << 16;
  return v.f;
}

__device__ inline void gload16(const void* g, void* l) {
  __builtin_amdgcn_global_load_lds(
      (const __attribute__((address_space(1))) void*)g,
      (__attribute__((address_space(3))) void*)l, 16, 0, 0);
}

// ---------------- im2col ----------------
__global__ __launch_bounds__(256) void im2col_k(const float* __restrict__ x,
                                                short* __restrict__ col) {
  int i = blockIdx.x * 256 + threadIdx.x;
  int r = i / KC, k = i % KC;
  short v = 0;
  if (k < 588) {
    int bt = r / 36, p = r % 36;
    int gy = p / 6, gx = p % 6;
    int c = k / 196, rem = k % 196;
    int ky = rem / 14, kx = rem % 14;
    v = f2bf(x[(((size_t)bt * 3 + c) * 84 + gy * 14 + ky) * 84 + gx * 14 + kx]);
  }
  col[i] = v;
}

// ---------------- conv weight prep ----------------
__global__ __launch_bounds__(256) void convw_k(const float* __restrict__ w,
                                               short* __restrict__ out) {
  int i = blockIdx.x * 256 + threadIdx.x;
  int n = i / KC, k = i % KC;
  out[i] = (k < 588) ? f2bf(w[(size_t)n * 588 + k]) : (short)0;
}

// ---------------- weight transpose+convert ----------------
__global__ __launch_bounds__(256) void wt_k(const float* __restrict__ in,
                                            short* __restrict__ out,
                                            int K, int N) {
  __shared__ float tile[32][33];
  const int l = blockIdx.z;
  in  += (size_t)l * K * N;
  out += (size_t)l * N * K;
  const int n0 = blockIdx.x * 32, k0 = blockIdx.y * 32;
  const int tx = threadIdx.x & 31, ty = threadIdx.x >> 5;
#pragma unroll
  for (int r = 0; r < 4; r++)
    tile[ty + 8 * r][tx] = in[(size_t)(k0 + ty + 8 * r) * N + n0 + tx];
  __syncthreads();
#pragma unroll
  for (int r = 0; r < 4; r++)
    out[(size_t)(n0 + ty + 8 * r) * K + k0 + tx] = f2bf(tile[tx][ty + 8 * r]);
}

// ---------------- token assembly ----------------
__global__ __launch_bounds__(256) void assemble_k(const float* __restrict__ conv_out,
                                                  const float* __restrict__ cls,
                                                  const float* __restrict__ pos,
                                                  float* __restrict__ X) {
  int i = blockIdx.x * 256 + threadIdx.x;
  int t = i / DM, d = i % DM;
  int bt = t / 37, n = t % 37;
  float v = (n == 0) ? cls[d] : conv_out[((size_t)bt * 36 + (n - 1)) * DM + d];
  X[i] = v + pos[n * DM + d];
}

// ---------------- temporal pos add ----------------
__global__ __launch_bounds__(256) void tpos_k(float* __restrict__ X,
                                              const float* __restrict__ tpos) {
  int i = blockIdx.x * 256 + threadIdx.x;
  int row = i / DM, d = i % DM;
  int tt = (row % 1184) / 37;
  X[i] += tpos[tt * DM + d];
}

// ---------------- LayerNorm ----------------
template <bool OBF>
__global__ __launch_bounds__(256) void ln_k(const float* __restrict__ in,
                                            const float* __restrict__ g,
                                            const float* __restrict__ b,
                                            void* __restrict__ outp) {
  int r = blockIdx.x;
  int tid = threadIdx.x;
  const float* xr = in + (size_t)r * DM;
  float v0 = xr[tid], v1 = xr[tid + 256], v2 = xr[tid + 512];
  float s  = v0 + v1 + v2;
  float sq = v0 * v0 + v1 * v1 + v2 * v2;
#pragma unroll
  for (int off = 32; off; off >>= 1) {
    s  += __shfl_down(s, off);
    sq += __shfl_down(sq, off);
  }
  __shared__ float ss[4], sg[4];
  if ((tid & 63) == 0) { ss[tid >> 6] = s; sg[tid >> 6] = sq; }
  __syncthreads();
  float S = ss[0] + ss[1] + ss[2] + ss[3];
  float Q = sg[0] + sg[1] + sg[2] + sg[3];
  float mean = S * (1.f / 768.f);
  float var  = Q * (1.f / 768.f) - mean * mean;
  float rs = rsqrtf(var + 1e-5f);
  float o0 = (v0 - mean) * rs * g[tid]       + b[tid];
  float o1 = (v1 - mean) * rs * g[tid + 256] + b[tid + 256];
  float o2 = (v2 - mean) * rs * g[tid + 512] + b[tid + 512];
  if (OBF) {
    short* o = (short*)outp + (size_t)r * DM;
    o[tid] = f2bf(o0); o[tid + 256] = f2bf(o1); o[tid + 512] = f2bf(o2);
  } else {
    float* o = (float*)outp + (size_t)r * DM;
    o[tid] = o0; o[tid + 256] = o1; o[tid + 512] = o2;
  }
}

// ---------------- fused double LayerNorm ----------------
__global__ __launch_bounds__(256) void ln2_k(const float* __restrict__ in,
                                             const float* __restrict__ g1,
                                             const float* __restrict__ b1,
                                             const float* __restrict__ g2,
                                             const float* __restrict__ b2,
                                             float* __restrict__ xn,
                                             short* __restrict__ w) {
  int r = blockIdx.x;
  int tid = threadIdx.x;
  const float* xr = in + (size_t)r * DM;
  float v0 = xr[tid], v1 = xr[tid + 256], v2 = xr[tid + 512];
  float s  = v0 + v1 + v2;
  float sq = v0 * v0 + v1 * v1 + v2 * v2;
#pragma unroll
  for (int off = 32; off; off >>= 1) {
    s  += __shfl_down(s, off);
    sq += __shfl_down(sq, off);
  }
  __shared__ float ss[4], sg[4], ss2[4], sg2[4];
  if ((tid & 63) == 0) { ss[tid >> 6] = s; sg[tid >> 6] = sq; }
  __syncthreads();
  float S = ss[0] + ss[1] + ss[2] + ss[3];
  float Q = sg[0] + sg[1] + sg[2] + sg[3];
  float mean = S * (1.f / 768.f);
  float var  = Q * (1.f / 768.f) - mean * mean;
  float rs = rsqrtf(var + 1e-5f);
  float x0 = (v0 - mean) * rs * g1[tid]       + b1[tid];
  float x1 = (v1 - mean) * rs * g1[tid + 256] + b1[tid + 256];
  float x2 = (v2 - mean) * rs * g1[tid + 512] + b1[tid + 512];
  float* xo = xn + (size_t)r * DM;
  xo[tid] = x0; xo[tid + 256] = x1; xo[tid + 512] = x2;
  float s2  = x0 + x1 + x2;
  float sq2 = x0 * x0 + x1 * x1 + x2 * x2;
#pragma unroll
  for (int off = 32; off; off >>= 1) {
    s2  += __shfl_down(s2, off);
    sq2 += __shfl_down(sq2, off);
  }
  if ((tid & 63) == 0) { ss2[tid >> 6] = s2; sg2[tid >> 6] = sq2; }
  __syncthreads();
  float S2 = ss2[0] + ss2[1] + ss2[2] + ss2[3];
  float Q2 = sg2[0] + sg2[1] + sg2[2] + sg2[3];
  float mean2 = S2 * (1.f / 768.f);
  float var2  = Q2 * (1.f / 768.f) - mean2 * mean2;
  float rs2 = rsqrtf(var2 + 1e-5f);
  short* wo = w + (size_t)r * DM;
  wo[tid]       = f2bf((x0 - mean2) * rs2 * g2[tid]       + b2[tid]);
  wo[tid + 256] = f2bf((x1 - mean2) * rs2 * g2[tid + 256] + b2[tid + 256]);
  wo[tid + 512] = f2bf((x2 - mean2) * rs2 * g2[tid + 512] + b2[tid + 512]);
}

// ---------------- MFMA bf16 GEMM: BK=32, 2-slot counted vmcnt (r16 best) ----
template <int BM, int BN, bool GELU, bool OBF, bool HASR1, bool HASR2>
__global__ __launch_bounds__(256, 4) void tgemm_k(const short* __restrict__ A,
                                                  const short* __restrict__ Bw,
                                                  const float* __restrict__ bias,
                                                  const float* __restrict__ r1,
                                                  const float* __restrict__ r2,
                                                  void* __restrict__ Cout,
                                                  int M, int N, int K) {
  constexpr int TM = BM / 2, TN = BN / 2;      // 2x2 waves
  constexpr int MF = TM / 16, NF = TN / 16;
  constexpr int ACH = BM / 64, BCH = BN / 64;
  constexpr int LOADS = ACH + BCH;

  __shared__ short As[2][BM][32];
  __shared__ short Bs[2][BN][32];

  const int nwg  = gridDim.x * gridDim.y;
  const int orig = blockIdx.x + gridDim.x * blockIdx.y;
  const int qq = nwg >> 3, rrm = nwg & 7;
  const int xcd = orig & 7, sub = orig >> 3;
  const int wgid = ((xcd < rrm) ? xcd * (qq + 1) : rrm * (qq + 1) + (xcd - rrm) * qq) + sub;
  const int bm = (wgid / gridDim.y) * BM, bn = (wgid % gridDim.y) * BN;

  const int tid = threadIdx.x, wid = tid >> 6, lane = tid & 63;
  const int lr = lane & 15, lg = lane >> 4;
  const int wm = wid >> 1, wn = wid & 1;

  const int srow = tid >> 2;
  const int sslot = (tid & 3) ^ ((srow >> 1) & 3);
  const short* Asrc = A  + (size_t)(bm + srow) * K + sslot * 8;
  const short* Bsrc = Bw + (size_t)(bn + srow) * K + sslot * 8;

  f32x4 acc[MF][NF];
#pragma unroll
  for (int m = 0; m < MF; m++)
#pragma unroll
    for (int n = 0; n < NF; n++) acc[m][n] = (f32x4){0.f, 0.f, 0.f, 0.f};

#define STAGE(slot, kk)                                                        \
  do {                                                                         \
    _Pragma("unroll")                                                          \
    for (int j = 0; j < ACH; j++)                                              \
      gload16(Asrc + (size_t)(j * 64) * K + (kk),                              \
              (char*)&As[slot][0][0] + j * 4096 + wid * 1024);                 \
    _Pragma("unroll")                                                          \
    for (int j = 0; j < BCH; j++)                                              \
      gload16(Bsrc + (size_t)(j * 64) * K + (kk),                              \
              (char*)&Bs[slot][0][0] + j * 4096 + wid * 1024);                 \
  } while (0)

  const int NT = K >> 5;
  const int rkey = (lr >> 1) & 3;

  STAGE(0, 0);
  for (int t = 0; t < NT; t++) {
    const int c = t & 1;
    if (t + 1 < NT) {
      STAGE(c ^ 1, (t + 1) << 5);
      if constexpr (LOADS == 4) asm volatile("s_waitcnt vmcnt(4)" ::: "memory");
      else                      asm volatile("s_waitcnt vmcnt(2)" ::: "memory");
    } else {
      asm volatile("s_waitcnt vmcnt(0)" ::: "memory");
    }
    __builtin_amdgcn_s_barrier();               // slot-c data visible to all

    bf16x8 aq[MF], bq[NF];
#pragma unroll
    for (int nf = 0; nf < NF; nf++) {
      const int row = wn * TN + nf * 16 + lr;
      bq[nf] = *reinterpret_cast<const bf16x8*>(
          (const char*)&Bs[c][0][0] + row * 64 + ((lg ^ rkey) << 4));
    }
#pragma unroll
    for (int mf = 0; mf < MF; mf++) {
      const int row = wm * TM + mf * 16 + lr;
      aq[mf] = *reinterpret_cast<const bf16x8*>(
          (const char*)&As[c][0][0] + row * 64 + ((lg ^ rkey) << 4));
    }
    __builtin_amdgcn_s_setprio(1);
#pragma unroll
    for (int mf = 0; mf < MF; mf++)
#pragma unroll
      for (int nf = 0; nf < NF; nf++)
        acc[mf][nf] = __builtin_amdgcn_mfma_f32_16x16x32_bf16(
            aq[mf], bq[nf], acc[mf][nf], 0, 0, 0);
    __builtin_amdgcn_s_setprio(0);
    __builtin_amdgcn_s_barrier();               // reads done before overwrite
  }
#undef STAGE

#pragma unroll
  for (int m = 0; m < MF; m++) {
#pragma unroll
    for (int r = 0; r < 4; r++) {
      int row = bm + wm * TM + m * 16 + lg * 4 + r;
      if (row < M) {
#pragma unroll
        for (int n = 0; n < NF; n++) {
          int col = bn + wn * TN + n * 16 + lr;
          size_t idx = (size_t)row * N + col;
          float v = acc[m][n][r];
          if (bias) v += bias[col];
          if (GELU) v = 0.5f * v * (1.f + erff(v * 0.70710678118654752f));
          if (HASR1) v += r1[idx];
          if (HASR2) v += r2[idx];
          if (OBF) ((short*)Cout)[idx] = f2bf(v);
          else     ((float*)Cout)[idx] = v;
        }
      }
    }
  }
}

// ---------------- attn v2-KV64 (spatial): exp2-domain, HW v_exp_f32 ---------
__global__ __launch_bounds__(256) void attn64_k(const short* __restrict__ qkv,
                                                short* __restrict__ out,
                                                int Bn, int Nn) {
  const int gx = gridDim.x, gy = gridDim.y;
  const int nwg = gx * gy;
  const int orig = blockIdx.x + gx * blockIdx.y;
  const int qq = nwg >> 3, rrm = nwg & 7;
  const int xcd = orig & 7, sub = orig >> 3;
  const int wgid = ((xcd < rrm) ? xcd * (qq + 1) : rrm * (qq + 1) + (xcd - rrm) * qq) + sub;
  const int bh = wgid / gy;
  const int qb = wgid % gy;
  const int b = bh / NHEAD, h = bh % NHEAD;
  const int q0 = qb * 64;

  const int tid = threadIdx.x;
  const int wid = tid >> 6, lane = tid & 63;
  const int lr = lane & 15, lg = lane >> 4;

  __shared__ short Ks[64][64];
  __shared__ short Vt[64][64];
  __shared__ short Ps[4][16][64];

  const int qrow_in = q0 + wid * 16 + lr;
  const int qcl = (qrow_in < Nn) ? qrow_in : (Nn - 1);
  const short* qp = qkv + ((size_t)(b * Nn + qcl)) * 2304 + h * 64 + lg * 8;
  bf16x8 qa0 = *reinterpret_cast<const bf16x8*>(qp);
  bf16x8 qa1 = *reinterpret_cast<const bf16x8*>(qp + 32);

  f32x4 oo[4];
#pragma unroll
  for (int dg = 0; dg < 4; dg++) oo[dg] = (f32x4){0.f, 0.f, 0.f, 0.f};
  float mm[4] = {-1e30f, -1e30f, -1e30f, -1e30f};
  float ll[4] = {0.f, 0.f, 0.f, 0.f};

  const int skey = tid >> 2;
  const int sdq  = (tid & 3) * 16;
  const int vkey = tid & 63;
  const int vd0  = wid * 16;

  const int swr = (lr & 7) << 3;

  for (int k0 = 0; k0 < Nn; k0 += 64) {
    {
      int kg = k0 + skey; if (kg >= Nn) kg = Nn - 1;
      const short* kp = qkv + ((size_t)(b * Nn + kg)) * 2304 + 768 + h * 64 + sdq;
      bf16x8 ka = *reinterpret_cast<const bf16x8*>(kp);
      bf16x8 kb = *reinterpret_cast<const bf16x8*>(kp + 8);
      const int ksw = (skey & 7) << 3;
      *reinterpret_cast<bf16x8*>(&Ks[skey][sdq ^ ksw])       = ka;
      *reinterpret_cast<bf16x8*>(&Ks[skey][(sdq + 8) ^ ksw]) = kb;
      int vg = k0 + vkey; if (vg >= Nn) vg = Nn - 1;
      const short* vp = qkv + ((size_t)(b * Nn + vg)) * 2304 + 1536 + h * 64 + vd0;
      bf16x8 va = *reinterpret_cast<const bf16x8*>(vp);
      bf16x8 vb = *reinterpret_cast<const bf16x8*>(vp + 8);
#pragma unroll
      for (int i = 0; i < 8; i++) {
        Vt[vd0 + i][vkey ^ (i << 3)]     = va[i];
        Vt[vd0 + 8 + i][vkey ^ (i << 3)] = vb[i];
      }
    }
    __syncthreads();

    f32x4 c[4];
#pragma unroll
    for (int kf = 0; kf < 4; kf++) {
      c[kf] = (f32x4){0.f, 0.f, 0.f, 0.f};
      const short* krow = &Ks[kf * 16 + lr][0];
      bf16x8 kb0 = *reinterpret_cast<const bf16x8*>(krow + ((lg * 8) ^ swr));
      c[kf] = __builtin_amdgcn_mfma_f32_16x16x32_bf16(qa0, kb0, c[kf], 0, 0, 0);
      bf16x8 kb1 = *reinterpret_cast<const bf16x8*>(krow + ((32 + lg * 8) ^ swr));
      c[kf] = __builtin_amdgcn_mfma_f32_16x16x32_bf16(qa1, kb1, c[kf], 0, 0, 0);
    }
#pragma unroll
    for (int kf = 0; kf < 4; kf++) {
#pragma unroll
      for (int r = 0; r < 4; r++) c[kf][r] *= (0.125f * LOG2E);  // log2 domain
      if (k0 + kf * 16 + lr >= Nn)
        c[kf][0] = c[kf][1] = c[kf][2] = c[kf][3] = -1e30f;
    }

    float tr[4];
#pragma unroll
    for (int r = 0; r < 4; r++) {
      float tv = fmaxf(fmaxf(c[0][r], c[1][r]), fmaxf(c[2][r], c[3][r]));
      tv = fmaxf(tv, __shfl_xor(tv, 1, 16));
      tv = fmaxf(tv, __shfl_xor(tv, 2, 16));
      tv = fmaxf(tv, __shfl_xor(tv, 4, 16));
      tv = fmaxf(tv, __shfl_xor(tv, 8, 16));
      tr[r] = tv;
    }
    const bool skipall = __all((tr[0] - mm[0] <= 8.f) & (tr[1] - mm[1] <= 8.f) &
                               (tr[2] - mm[2] <= 8.f) & (tr[3] - mm[3] <= 8.f));
#pragma unroll
    for (int r = 0; r < 4; r++) {
      if (!skipall) {
        float mn = fmaxf(mm[r], tr[r]);
        float sc = __builtin_amdgcn_exp2f(mm[r] - mn);
        ll[r] *= sc;
        oo[0][r] *= sc; oo[1][r] *= sc; oo[2][r] *= sc; oo[3][r] *= sc;
        mm[r] = mn;
      }
      float p0 = __builtin_amdgcn_exp2f(c[0][r] - mm[r]);
      float p1 = __builtin_amdgcn_exp2f(c[1][r] - mm[r]);
      float p2 = __builtin_amdgcn_exp2f(c[2][r] - mm[r]);
      float p3 = __builtin_amdgcn_exp2f(c[3][r] - mm[r]);
      float ps = (p0 + p1) + (p2 + p3);
      ps += __shfl_xor(ps, 1, 16);
      ps += __shfl_xor(ps, 2, 16);
      ps += __shfl_xor(ps, 4, 16);
      ps += __shfl_xor(ps, 8, 16);
      ll[r] += ps;
      const int prow = lg * 4 + r;
      const int psw  = (prow & 7) << 3;
      short* pr = &Ps[wid][prow][0];
      pr[lr ^ psw]        = f2bf(p0);
      pr[(16 + lr) ^ psw] = f2bf(p1);
      pr[(32 + lr) ^ psw] = f2bf(p2);
      pr[(48 + lr) ^ psw] = f2bf(p3);
    }

#pragma unroll
    for (int ks = 0; ks < 2; ks++) {
      bf16x8 pa = *reinterpret_cast<const bf16x8*>(&Ps[wid][lr][(ks * 32 + lg * 8) ^ swr]);
#pragma unroll
      for (int dg = 0; dg < 4; dg++) {
        bf16x8 vb = *reinterpret_cast<const bf16x8*>(
            &Vt[dg * 16 + lr][(ks * 32 + lg * 8) ^ swr]);
        oo[dg] = __builtin_amdgcn_mfma_f32_16x16x32_bf16(pa, vb, oo[dg], 0, 0, 0);
      }
    }
    __syncthreads();
  }

#pragma unroll
  for (int r = 0; r < 4; r++) {
    int qr = q0 + wid * 16 + lg * 4 + r;
    if (qr < Nn) {
      float inv = 1.f / ll[r];
      short* op = out + ((size_t)(b * Nn + qr)) * DM + h * 64 + lr;
      op[0]  = f2bf(oo[0][r] * inv);
      op[16] = f2bf(oo[1][r] * inv);
      op[32] = f2bf(oo[2][r] * inv);
      op[48] = f2bf(oo[3][r] * inv);
    }
  }
}

// ---------------- attn v3-Q128-KV128 (temporal): exp2-domain, HW v_exp_f32 ---
__global__ __launch_bounds__(512) void attnT_k(const short* __restrict__ qkv,
                                               short* __restrict__ out,
                                               int Bn, int Nn) {
  const int gx = gridDim.x, gy = gridDim.y;
  const int nwg = gx * gy;
  const int orig = blockIdx.x + gx * blockIdx.y;
  const int qq = nwg >> 3, rrm = nwg & 7;
  const int xcd = orig & 7, sub = orig >> 3;
  const int wgid = ((xcd < rrm) ? xcd * (qq + 1) : rrm * (qq + 1) + (xcd - rrm) * qq) + sub;
  const int bh = wgid / gy;
  const int qb = wgid % gy;
  const int b = bh / NHEAD, h = bh % NHEAD;
  const int q0 = qb * 128;

  const int tid = threadIdx.x;
  const int wid = tid >> 6, lane = tid & 63;     // wid 0..7
  const int lr = lane & 15, lg = lane >> 4;

  __shared__ short Ks[128][64];     // 16KB
  __shared__ short Vt[64][128];     // 16KB
  __shared__ short Ps[8][16][128];  // 32KB

  const int qrow_in = q0 + wid * 16 + lr;
  const int qcl = (qrow_in < Nn) ? qrow_in : (Nn - 1);
  const short* qp = qkv + ((size_t)(b * Nn + qcl)) * 2304 + h * 64 + lg * 8;
  bf16x8 qa0 = *reinterpret_cast<const bf16x8*>(qp);
  bf16x8 qa1 = *reinterpret_cast<const bf16x8*>(qp + 32);
#pragma unroll
  for (int j = 0; j < 8; j++) {      // fold 1/8 * log2e into Q: scores in log2
    qa0[j] = f2bf(bf2f(qa0[j]) * (0.125f * LOG2E));
    qa1[j] = f2bf(bf2f(qa1[j]) * (0.125f * LOG2E));
  }

  f32x4 oo[4];
#pragma unroll
  for (int dg = 0; dg < 4; dg++) oo[dg] = (f32x4){0.f, 0.f, 0.f, 0.f};
  float mm[4] = {-1e30f, -1e30f, -1e30f, -1e30f};
  float ll[4] = {0.f, 0.f, 0.f, 0.f};

  const int skey = tid >> 2;            // K: key row 0..127
  const int sdq  = (tid & 3) * 16;      // K: d offset 0/16/32/48
  const int vkeyc = tid & 127;          // V: key 0..127
  const int vd0   = (tid >> 7) * 16;    // V: d range via tid bits 7-8
  const int swr = (lr & 7) << 3;
  const int ksw = (skey & 7) << 3;

  for (int k0 = 0; k0 < Nn; k0 += 128) {
    {
      int kg = k0 + skey; if (kg >= Nn) kg = Nn - 1;
      const short* kp = qkv + ((size_t)(b * Nn + kg)) * 2304 + 768 + h * 64 + sdq;
      bf16x8 k0v = *reinterpret_cast<const bf16x8*>(kp);
      bf16x8 k1v = *reinterpret_cast<const bf16x8*>(kp + 8);
      *reinterpret_cast<bf16x8*>(&Ks[skey][(sdq +  0) ^ ksw]) = k0v;
      *reinterpret_cast<bf16x8*>(&Ks[skey][(sdq +  8) ^ ksw]) = k1v;
      int vg = k0 + vkeyc; if (vg >= Nn) vg = Nn - 1;
      const short* vp = qkv + ((size_t)(b * Nn + vg)) * 2304 + 1536 + h * 64 + vd0;
      bf16x8 v0 = *reinterpret_cast<const bf16x8*>(vp);
      bf16x8 v1 = *reinterpret_cast<const bf16x8*>(vp + 8);
#pragma unroll
      for (int i = 0; i < 8; i++) {
        Vt[vd0 + i]    [vkeyc ^ (i << 3)] = v0[i];
        Vt[vd0 + 8 + i][vkeyc ^ (i << 3)] = v1[i];
      }
    }
    __syncthreads();

    f32x4 c[8];
#pragma unroll
    for (int kf = 0; kf < 8; kf++) {
      c[kf] = (f32x4){0.f, 0.f, 0.f, 0.f};
      const short* krow = &Ks[kf * 16 + lr][0];
      bf16x8 kq0 = *reinterpret_cast<const bf16x8*>(krow + ((lg * 8) ^ swr));
      c[kf] = __builtin_amdgcn_mfma_f32_16x16x32_bf16(qa0, kq0, c[kf], 0, 0, 0);
      bf16x8 kq1 = *reinterpret_cast<const bf16x8*>(krow + ((32 + lg * 8) ^ swr));
      c[kf] = __builtin_amdgcn_mfma_f32_16x16x32_bf16(qa1, kq1, c[kf], 0, 0, 0);
    }
#pragma unroll
    for (int kf = 0; kf < 8; kf++) {
      if (k0 + kf * 16 + lr >= Nn)
        c[kf][0] = c[kf][1] = c[kf][2] = c[kf][3] = -1e30f;
    }

    float tr[4];
#pragma unroll
    for (int r = 0; r < 4; r++) {
      float tv = fmaxf(fmaxf(fmaxf(c[0][r], c[1][r]), fmaxf(c[2][r], c[3][r])),
                       fmaxf(fmaxf(c[4][r], c[5][r]), fmaxf(c[6][r], c[7][r])));
      tv = fmaxf(tv, __shfl_xor(tv, 1, 16));
      tv = fmaxf(tv, __shfl_xor(tv, 2, 16));
      tv = fmaxf(tv, __shfl_xor(tv, 4, 16));
      tv = fmaxf(tv, __shfl_xor(tv, 8, 16));
      tr[r] = tv;
    }
    const bool skipall = __all((tr[0] - mm[0] <= 8.f) & (tr[1] - mm[1] <= 8.f) &
                               (tr[2] - mm[2] <= 8.f) & (tr[3] - mm[3] <= 8.f));
#pragma unroll
    for (int r = 0; r < 4; r++) {
      if (!skipall) {
        float mn = fmaxf(mm[r], tr[r]);
        float sc = __builtin_amdgcn_exp2f(mm[r] - mn);
        ll[r] *= sc;
        oo[0][r] *= sc; oo[1][r] *= sc; oo[2][r] *= sc; oo[3][r] *= sc;
        mm[r] = mn;
      }
      float p[8], ps = 0.f;
#pragma unroll
      for (int kf = 0; kf < 8; kf++) {
        p[kf] = __builtin_amdgcn_exp2f(c[kf][r] - mm[r]);
        ps += p[kf];
      }
      ps += __shfl_xor(ps, 1, 16);
      ps += __shfl_xor(ps, 2, 16);
      ps += __shfl_xor(ps, 4, 16);
      ps += __shfl_xor(ps, 8, 16);
      ll[r] += ps;
      const int prow = lg * 4 + r;
      const int psw  = (prow & 7) << 3;
      short* pr = &Ps[wid][prow][0];
#pragma unroll
      for (int kf = 0; kf < 8; kf++)
        pr[(kf * 16 + lr) ^ psw] = f2bf(p[kf]);
    }

#pragma unroll
    for (int ks = 0; ks < 4; ks++) {
      bf16x8 pa = *reinterpret_cast<const bf16x8*>(
          &Ps[wid][lr][(ks * 32 + lg * 8) ^ swr]);
#pragma unroll
      for (int dg = 0; dg < 4; dg++) {
        bf16x8 vq = *reinterpret_cast<const bf16x8*>(
            &Vt[dg * 16 + lr][(ks * 32 + lg * 8) ^ swr]);
        oo[dg] = __builtin_amdgcn_mfma_f32_16x16x32_bf16(pa, vq, oo[dg], 0, 0, 0);
      }
    }
    __syncthreads();
  }

#pragma unroll
  for (int r = 0; r < 4; r++) {
    int qr = q0 + wid * 16 + lg * 4 + r;
    if (qr < Nn) {
      float inv = 1.f / ll[r];
      short* op = out + ((size_t)(b * Nn + qr)) * DM + h * 64 + lr;
      op[0]  = f2bf(oo[0][r] * inv);
      op[16] = f2bf(oo[1][r] * inv);
      op[32] = f2bf(oo[2][r] * inv);
      op[48] = f2bf(oo[3][r] * inv);
    }
  }
}

// ---------------- mean over sequence, two-pass ----------------
__global__ __launch_bounds__(256) void mean1_k(const float* __restrict__ X,
                                               float* __restrict__ P) {
  int b = blockIdx.x, seg = blockIdx.z;
  int d = blockIdx.y * 256 + threadIdx.x;
  int r0 = seg * 148;
  float s = 0.f;
  for (int r = r0; r < r0 + 148; r++) s += X[((size_t)b * 1184 + r) * DM + d];
  P[((size_t)(b * 8 + seg)) * DM + d] = s;
}
__global__ __launch_bounds__(256) void mean2_k(const float* __restrict__ P,
                                               float* __restrict__ out) {
  int b = blockIdx.x;
  int d = blockIdx.y * 256 + threadIdx.x;
  float s = 0.f;
#pragma unroll
  for (int seg = 0; seg < 8; seg++) s += P[((size_t)(b * 8 + seg)) * DM + d];
  out[b * DM + d] = s * (1.f / 1184.f);
}

// ---------------- orchestration ----------------
extern "C" void kernel_launch(void* const* d_in, const int* in_sizes, int n_in,
                              void* d_out, int out_size, void* d_ws, size_t ws_size,
                              hipStream_t stream) {
  (void)in_sizes; (void)n_in; (void)out_size; (void)ws_size;
  const float* x      = (const float*)d_in[0];
  const float* conv_w = (const float*)d_in[1];
  const float* conv_b = (const float*)d_in[2];
  const float* cls    = (const float*)d_in[3];
  const float* pos    = (const float*)d_in[4];
  const float* tpos   = (const float*)d_in[5];
  const float* W[2][14];
  for (int p = 0; p < 2; p++)
    for (int i = 0; i < 14; i++)
      W[p][i] = (const float*)d_in[6 + p * 14 + i];

  char* ws = (char*)d_ws;
  const size_t TOKF = (size_t)NTOK * DM * 4;
  float* X    = (float*)(ws);
  float* XN   = (float*)(ws + TOKF);
  float* Y    = (float*)(ws + 2 * TOKF);
  short* TA2  = (short*)(ws + 3 * TOKF);
  short* BIG  = (short*)(ws + 3 * TOKF + (size_t)NTOK * DM * 2);
  short* WB   = (short*)(ws + 3 * TOKF + (size_t)NTOK * DM * 2
                            + (size_t)NTOK * 3072 * 2);
  const size_t QE = (size_t)3 * 2304 * 768;
  const size_t PE = (size_t)3 * 768 * 768;
  const size_t F1E = (size_t)3 * 3072 * 768;
  const size_t F2E = (size_t)3 * 768 * 3072;
  const size_t PFX = QE + PE + F1E + F2E;
  short* WQ[2], *WP[2], *WF1[2], *WF2[2];
  for (int p = 0; p < 2; p++) {
    WQ[p]  = WB + p * PFX;
    WP[p]  = WQ[p] + QE;
    WF1[p] = WP[p] + PE;
    WF2[p] = WF1[p] + F1E;
  }
  short* CW = WB + 2 * PFX;
  float* PB = (float*)(CW + (size_t)768 * KC);

  for (int p = 0; p < 2; p++) {
    wt_k<<<dim3(72, 24, 3), 256, 0, stream>>>(W[p][4],  WQ[p],  768, 2304);
    wt_k<<<dim3(24, 24, 3), 256, 0, stream>>>(W[p][6],  WP[p],  768, 768);
    wt_k<<<dim3(96, 24, 3), 256, 0, stream>>>(W[p][10], WF1[p], 768, 3072);
    wt_k<<<dim3(24, 96, 3), 256, 0, stream>>>(W[p][12], WF2[p], 3072, 768);
  }
  convw_k<<<1920, 256, 0, stream>>>(conv_w, CW);

  im2col_k<<<11520, 256, 0, stream>>>(x, BIG);
  tgemm_k<64, 64, false, false, false, false><<<dim3(72, 12), 256, 0, stream>>>(
      BIG, CW, conv_b, nullptr, nullptr, Y, 4608, 768, KC);
  assemble_k<<<14208, 256, 0, stream>>>(Y, cls, pos, X);

  for (int phase = 0; phase < 2; phase++) {
    const int Bn = (phase == 0) ? 128 : 4;
    const int Nn = (phase == 0) ? 37 : 1184;
    if (phase == 1) tpos_k<<<14208, 256, 0, stream>>>(X, tpos);
    for (int i = 0; i < 3; i++) {
      const float* pre_g = W[phase][0] + i * DM;
      const float* pre_b = W[phase][1] + i * DM;
      const float* n1_g  = W[phase][2] + i * DM;
      const float* n1_b  = W[phase][3] + i * DM;
      const float* qkv_b = W[phase][5] + i * 2304;
      const float* prj_b = W[phase][7] + i * DM;
      const float* n2_g  = W[phase][8] + i * DM;
      const float* n2_b  = W[phase][9] + i * DM;
      const float* fc1_b = W[phase][11] + i * 3072;
      const float* fc2_b = W[phase][13] + i * DM;
      const short* qkv_w = WQ[phase]  + (size_t)i * 2304 * 768;
      const short* prj_w = WP[phase]  + (size_t)i * 768 * 768;
      const short* fc1_w = WF1[phase] + (size_t)i * 3072 * 768;
      const short* fc2_w = WF2[phase] + (size_t)i * 768 * 3072;

      ln2_k<<<NTOK, 256, 0, stream>>>(X, pre_g, pre_b, n1_g, n1_b, XN, TA2);
      tgemm_k<128, 128, false, true, false, false><<<dim3(37, 18), 256, 0, stream>>>(
          TA2, qkv_w, qkv_b, nullptr, nullptr, BIG, NTOK, 2304, DM);
      if (phase == 0)
        attn64_k<<<dim3(Bn * NHEAD, (Nn + 63) / 64), 256, 0, stream>>>(BIG, TA2, Bn, Nn);
      else
        attnT_k<<<dim3(Bn * NHEAD, (Nn + 127) / 128), 512, 0, stream>>>(BIG, TA2, Bn, Nn);
      tgemm_k<64, 64, false, false, true, false><<<dim3(74, 12), 256, 0, stream>>>(
          TA2, prj_w, prj_b, XN, nullptr, Y, NTOK, DM, DM);
      ln_k<true><<<NTOK, 256, 0, stream>>>(Y, n2_g, n2_b, TA2);
      tgemm_k<128, 128, true, true, false, false><<<dim3(37, 24), 256, 0, stream>>>(
          TA2, fc1_w, fc1_b, nullptr, nullptr, BIG, NTOK, 3072, DM);
      tgemm_k<64, 64, false, false, true, true><<<dim3(74, 12), 256, 0, stream>>>(
          BIG, fc2_w, fc2_b, Y, X, X, NTOK, DM, 3072);
    }
  }
  mean1_k<<<dim3(4, 3, 8), 256, 0, stream>>>(X, PB);
  mean2_k<<<dim3(4, 3), 256, 0, stream>>>(PB, (float*)d_out);
}